// Round 13
// baseline (490.723 us; speedup 1.0000x reference)
//
#include <hip/hip_runtime.h>
#include <math.h>

// Problem constants
#define BB   4
#define CIN  512
#define DD   256
#define NP   1600      // tokens per image (40*40)
#define TT   (BB*NP)   // 6400 total tokens
#define FF   2048
#define NHH  8
#define HDD  32
#define NA   3
#define NC   80

typedef __attribute__((ext_vector_type(8))) short bf16x8_t;
typedef __attribute__((ext_vector_type(4))) float f32x4_t;
typedef __attribute__((ext_vector_type(16))) float f32x16_t;

static __device__ __forceinline__ ushort f2bf(float f) {
    unsigned int u = __float_as_uint(f);
    u += 0x7FFF + ((u >> 16) & 1);          // round-to-nearest-even
    return (ushort)(u >> 16);
}
static __device__ __forceinline__ float bf2f(ushort u) {
    return __uint_as_float((unsigned int)u << 16);
}
// pack 2 f32 -> 1 u32 of 2 bf16 (RNE), single v_cvt_pk_bf16_f32
static __device__ __forceinline__ unsigned int cvt_pk_bf16(float lo, float hi) {
    unsigned int r;
    asm("v_cvt_pk_bf16_f32 %0, %1, %2" : "=v"(r) : "v"(lo), "v"(hi));
    return r;
}
// exchange a.lanes[half] <-> b.lanes[other half]
static __device__ __forceinline__ void swap32(unsigned int& a, unsigned int& b) {
    asm("v_permlane32_swap_b32 %0, %1" : "+v"(a), "+v"(b));
}
static __device__ __forceinline__ bf16x8_t pack4(unsigned int a, unsigned int b,
                                                 unsigned int c, unsigned int d) {
    union { uint4 u; bf16x8_t v; } t;
    t.u = make_uint4(a, b, c, d);
    return t.v;
}

// ---------------------------------------------------------------------------
// Weight prep: batched transpose + scale + fp32->bf16.
// ---------------------------------------------------------------------------
struct WDesc { const float* src; ushort* dst; int R; int C; int ntiles; float scale; };
struct WPrep { WDesc d[16]; };

__global__ __launch_bounds__(256) void wprep_kernel(WPrep p) {
    __shared__ float tile[32][33];
    int t = blockIdx.x;
    int i = 0;
    while (t >= p.d[i].ntiles) { t -= p.d[i].ntiles; i++; }
    const float* src = p.d[i].src;
    ushort* dst = p.d[i].dst;
    int R = p.d[i].R, C = p.d[i].C;
    float sc = p.d[i].scale;
    int tC = C >> 5;
    int r0 = (t / tC) * 32, c0 = (t % tC) * 32;
    int tx = threadIdx.x, ty = threadIdx.y;
    #pragma unroll
    for (int j = 0; j < 32; j += 8)
        tile[ty + j][tx] = src[(size_t)(r0 + ty + j) * C + (c0 + tx)];
    __syncthreads();
    #pragma unroll
    for (int j = 0; j < 32; j += 8)
        dst[(size_t)(c0 + ty + j) * R + (r0 + tx)] = f2bf(tile[tx][ty + j] * sc);
}

// ---------------------------------------------------------------------------
// Head-2 combined weight prep: Bt [384][256] bf16 (cls|pad|box|pad|obj)
// ---------------------------------------------------------------------------
__global__ __launch_bounds__(256) void head2_wprep_kernel(
        const float* __restrict__ cls_w2, const float* __restrict__ box_w2,
        const float* __restrict__ obj_w2, ushort* __restrict__ dst)
{
    int nrow = blockIdx.x;      // 0..383
    int k = threadIdx.x;        // 0..255
    float v = 0.f;
    if (nrow < 240)                      v = cls_w2[k * 240 + nrow];
    else if (nrow >= 256 && nrow < 268)  v = box_w2[k * 12 + (nrow - 256)];
    else if (nrow >= 320 && nrow < 323)  v = obj_w2[k * 3 + (nrow - 320)];
    dst[(size_t)nrow * 256 + k] = f2bf(v);
}

// ---------------------------------------------------------------------------
// Transpose x [B][CIN][NP] f32 -> xT [T][CIN] bf16
// ---------------------------------------------------------------------------
__global__ void transpose_x_kernel(const float* __restrict__ x, ushort* __restrict__ xT) {
    __shared__ float tile[32][33];
    int b  = blockIdx.z;
    int c0 = blockIdx.x * 32;
    int n0 = blockIdx.y * 32;
    int tx = threadIdx.x, ty = threadIdx.y;
    #pragma unroll
    for (int j = 0; j < 32; j += 8) {
        tile[ty + j][tx] = x[b * CIN * NP + (c0 + ty + j) * NP + (n0 + tx)];
    }
    __syncthreads();
    #pragma unroll
    for (int j = 0; j < 32; j += 8) {
        xT[(size_t)(b * NP + n0 + ty + j) * CIN + (c0 + tx)] = f2bf(tile[tx][ty + j]);
    }
}

// ---------------------------------------------------------------------------
// Shared GEMM core (bf16 A): 64x64 tiles, 4 waves x one 32x32 fragment.
// ---------------------------------------------------------------------------
#define GEMM_CORE_LDA(A_, Bt_, K_, LDA_)                                         \
    __shared__ ushort As[64][72];                                                \
    __shared__ ushort Bs[64][72];                                                \
    int tid  = threadIdx.x;                                                      \
    int lane = tid & 63, wid = tid >> 6;                                         \
    int wm = wid >> 1, wn = wid & 1;                                             \
    int m0 = blockIdx.y * 64, n0 = blockIdx.x * 64;                              \
    int ln31 = lane & 31, lg = lane >> 5;                                        \
    int srow = tid >> 2;                                                         \
    int scol = (tid & 3) * 16;                                                   \
    const ushort* ag = (A_)  + (size_t)(m0 + srow) * (LDA_) + scol;              \
    const ushort* bg = (Bt_) + (size_t)(n0 + srow) * (K_) + scol;                \
    f32x16_t acc = {};                                                           \
    for (int k0 = 0; k0 < (K_); k0 += 64) {                                      \
        uint4 av0 = *(const uint4*)(ag + k0);                                    \
        uint4 av1 = *(const uint4*)(ag + k0 + 8);                                \
        uint4 bv0 = *(const uint4*)(bg + k0);                                    \
        uint4 bv1 = *(const uint4*)(bg + k0 + 8);                                \
        *(uint4*)&As[srow][scol]     = av0;                                      \
        *(uint4*)&As[srow][scol + 8] = av1;                                      \
        *(uint4*)&Bs[srow][scol]     = bv0;                                      \
        *(uint4*)&Bs[srow][scol + 8] = bv1;                                      \
        __syncthreads();                                                         \
        _Pragma("unroll")                                                        \
        for (int kc = 0; kc < 4; kc++) {                                         \
            bf16x8_t af = *(const bf16x8_t*)&As[wm * 32 + ln31][kc * 16 + lg * 8]; \
            bf16x8_t bf = *(const bf16x8_t*)&Bs[wn * 32 + ln31][kc * 16 + lg * 8]; \
            acc = __builtin_amdgcn_mfma_f32_32x32x16_bf16(af, bf, acc, 0, 0, 0); \
        }                                                                        \
        __syncthreads();                                                         \
    }                                                                            \
    int n = n0 + wn * 32 + ln31;

#define GEMM_CORE(A_, Bt_, K_) GEMM_CORE_LDA(A_, Bt_, K_, K_)

// ---------------------------------------------------------------------------
// LN-fused GEMM core: A = f32 [M][256] with per-row LayerNorm applied during
// staging (full K=256 A-tile in LDS, stats in f32 = ln_kernel math).
// ---------------------------------------------------------------------------
#define GEMM_LN_CORE(HF_, Bt_, LNS_, LNB_)                                       \
    __shared__ ushort Asf[64][264];                                              \
    __shared__ ushort Bs[64][72];                                                \
    __shared__ float red1[64][4];                                                \
    __shared__ float red2[64][4];                                                \
    int tid  = threadIdx.x;                                                      \
    int lane = tid & 63, wid = tid >> 6;                                         \
    int wm = wid >> 1, wn = wid & 1;                                             \
    int m0 = blockIdx.y * 64, n0 = blockIdx.x * 64;                              \
    int ln31 = lane & 31, lg = lane >> 5;                                        \
    int srow = tid >> 2;                                                         \
    int scol = (tid & 3) * 16;                                                   \
    {                                                                            \
        int r = tid >> 2, qd = tid & 3;                                          \
        const float* hrow = (HF_) + (size_t)(m0 + r) * DD + qd * 64;             \
        float s1 = 0.f, s2 = 0.f;                                                \
        _Pragma("unroll")                                                        \
        for (int j = 0; j < 64; j += 4) {                                        \
            float4 v = *(const float4*)(hrow + j);                               \
            s1 += (v.x + v.y) + (v.z + v.w);                                     \
            s2 += (v.x * v.x + v.y * v.y) + (v.z * v.z + v.w * v.w);             \
        }                                                                        \
        red1[r][qd] = s1; red2[r][qd] = s2;                                      \
        __syncthreads();                                                         \
        float S1 = (red1[r][0] + red1[r][1]) + (red1[r][2] + red1[r][3]);        \
        float S2 = (red2[r][0] + red2[r][1]) + (red2[r][2] + red2[r][3]);        \
        float mean = S1 * (1.f / DD);                                            \
        float var  = S2 * (1.f / DD) - mean * mean;                              \
        float inv  = rsqrtf(var + 1e-5f);                                        \
        _Pragma("unroll")                                                        \
        for (int j = 0; j < 64; j += 4) {                                        \
            float4 v  = *(const float4*)(hrow + j);                              \
            int c = qd * 64 + j;                                                 \
            float4 sv = *(const float4*)((LNS_) + c);                            \
            float4 bv = *(const float4*)((LNB_) + c);                            \
            ushort4 w;                                                           \
            w.x = f2bf((v.x - mean) * inv * sv.x + bv.x);                        \
            w.y = f2bf((v.y - mean) * inv * sv.y + bv.y);                        \
            w.z = f2bf((v.z - mean) * inv * sv.z + bv.z);                        \
            w.w = f2bf((v.w - mean) * inv * sv.w + bv.w);                        \
            *(ushort4*)&Asf[r][c] = w;                                           \
        }                                                                        \
    }                                                                            \
    const ushort* bg = (Bt_) + (size_t)(n0 + srow) * DD + scol;                  \
    f32x16_t acc = {};                                                           \
    __syncthreads();                                                             \
    for (int k0 = 0; k0 < DD; k0 += 64) {                                        \
        uint4 bv0 = *(const uint4*)(bg + k0);                                    \
        uint4 bv1 = *(const uint4*)(bg + k0 + 8);                                \
        *(uint4*)&Bs[srow][scol]     = bv0;                                      \
        *(uint4*)&Bs[srow][scol + 8] = bv1;                                      \
        __syncthreads();                                                         \
        _Pragma("unroll")                                                        \
        for (int kc = 0; kc < 4; kc++) {                                         \
            bf16x8_t af = *(const bf16x8_t*)&Asf[wm * 32 + ln31][k0 + kc * 16 + lg * 8]; \
            bf16x8_t bf = *(const bf16x8_t*)&Bs[wn * 32 + ln31][kc * 16 + lg * 8];       \
            acc = __builtin_amdgcn_mfma_f32_32x32x16_bf16(af, bf, acc, 0, 0, 0); \
        }                                                                        \
        __syncthreads();                                                         \
    }                                                                            \
    int n = n0 + wn * 32 + ln31;

// ---------------------------------------------------------------------------
// Generic MFMA bf16 GEMM: + bias (+bias2) (+residual f32), opt ReLU.
// ---------------------------------------------------------------------------
__global__ __launch_bounds__(256) void gemm_mfma_kernel(
        const ushort* __restrict__ A, const ushort* __restrict__ Bt,
        const float* __restrict__ bias, const float* __restrict__ bias2,
        const float* __restrict__ residual, float* __restrict__ Cf,
        ushort* __restrict__ Cbf, int M, int N, int K, int do_relu)
{
    GEMM_CORE(A, Bt, K)
    float bsum = bias[n] + (bias2 ? bias2[n] : 0.f);
    #pragma unroll
    for (int r = 0; r < 16; r++) {
        int row = (r & 3) + 8 * (r >> 2) + 4 * lg;
        int m = m0 + wm * 32 + row;
        float v = acc[r] + bsum;
        if (do_relu) v = fmaxf(v, 0.f);
        if (residual) v += residual[(size_t)m * N + n];
        if (Cf)  Cf [(size_t)m * N + n] = v;
        if (Cbf) Cbf[(size_t)m * N + n] = f2bf(v);
    }
}

// ---------------------------------------------------------------------------
// LN-fused QKV GEMM: A = h (f32) -> LN -> @ qkvT [768][256].
// Segments: n<256 q_out bf16 (bias*qscale), n<512 k_out, else Vt scatter.
// ---------------------------------------------------------------------------
__global__ __launch_bounds__(256) void gemm_ln_qkv_kernel(
        const float* __restrict__ hf, const ushort* __restrict__ Bt,
        const float* __restrict__ lns, const float* __restrict__ lnb,
        const float* __restrict__ qb, const float* __restrict__ kb,
        const float* __restrict__ vb, ushort* __restrict__ q_out,
        ushort* __restrict__ k_out, ushort* __restrict__ vt_out, float qscale)
{
    GEMM_LN_CORE(hf, Bt, lns, lnb)
    int seg = n >> 8;
    int c   = n & 255;
    if (seg == 0) {
        float bsum = qb[c] * qscale;
        #pragma unroll
        for (int r = 0; r < 16; r++) {
            int row = (r & 3) + 8 * (r >> 2) + 4 * lg;
            q_out[(size_t)(m0 + wm * 32 + row) * DD + c] = f2bf(acc[r] + bsum);
        }
    } else if (seg == 1) {
        float bsum = kb[c];
        #pragma unroll
        for (int r = 0; r < 16; r++) {
            int row = (r & 3) + 8 * (r >> 2) + 4 * lg;
            k_out[(size_t)(m0 + wm * 32 + row) * DD + c] = f2bf(acc[r] + bsum);
        }
    } else {
        float bsum = vb[c];
        int b = m0 / NP;
        int nn0 = m0 - b * NP + wm * 32 + 4 * lg;
        int hh = c >> 5, d = c & 31;
        ushort* vt = vt_out + ((size_t)(b * NHH + hh) * HDD + d) * NP + nn0;
        #pragma unroll
        for (int qq = 0; qq < 4; qq++) {
            ushort4 w4 = make_ushort4(f2bf(acc[qq * 4 + 0] + bsum), f2bf(acc[qq * 4 + 1] + bsum),
                                      f2bf(acc[qq * 4 + 2] + bsum), f2bf(acc[qq * 4 + 3] + bsum));
            *(ushort4*)(vt + 8 * qq) = w4;
        }
    }
}

// ---------------------------------------------------------------------------
// LN-fused FFN1 GEMM: A = h (f32) -> LN -> @ f1wT [2048][256], ReLU, bf16 out.
// ---------------------------------------------------------------------------
__global__ __launch_bounds__(256) void gemm_ln_ffn1_kernel(
        const float* __restrict__ hf, const ushort* __restrict__ Bt,
        const float* __restrict__ lns, const float* __restrict__ lnb,
        const float* __restrict__ bias, ushort* __restrict__ Cbf)
{
    GEMM_LN_CORE(hf, Bt, lns, lnb)
    float bsum = bias[n];
    #pragma unroll
    for (int r = 0; r < 16; r++) {
        int row = (r & 3) + 8 * (r >> 2) + 4 * lg;
        float v = fmaxf(acc[r] + bsum, 0.f);
        Cbf[(size_t)(m0 + wm * 32 + row) * FF + n] = f2bf(v);
    }
}

// ---------------------------------------------------------------------------
// Fused heads layer-1 GEMM -> t1 [T][768] bf16 (ReLU)
// ---------------------------------------------------------------------------
__global__ __launch_bounds__(256) void gemm_head1_kernel(
        const ushort* __restrict__ A, const ushort* __restrict__ Bt,
        const float* __restrict__ b0, const float* __restrict__ b1,
        const float* __restrict__ b2, ushort* __restrict__ t1)
{
    GEMM_CORE(A, Bt, DD)
    int seg = n >> 8;
    int c   = n & 255;
    float bsum = (seg == 0) ? b0[c] : (seg == 1) ? b1[c] : b2[c];
    #pragma unroll
    for (int r = 0; r < 16; r++) {
        int row = (r & 3) + 8 * (r >> 2) + 4 * lg;
        float v = fmaxf(acc[r] + bsum, 0.f);
        t1[(size_t)(m0 + wm * 32 + row) * 768 + n] = f2bf(v);
    }
}

// ---------------------------------------------------------------------------
// Fused heads layer-2 GEMM: N=384 combined; scatters into [B,NA,H,W,S] outs.
// ---------------------------------------------------------------------------
__global__ __launch_bounds__(256) void gemm_head2_kernel(
        const ushort* __restrict__ t1, const ushort* __restrict__ Bt,
        const float* __restrict__ cb, const float* __restrict__ bb,
        const float* __restrict__ ob, float* __restrict__ cls_out,
        float* __restrict__ box_out, float* __restrict__ obj_out)
{
    int n0_ = blockIdx.x * 64;
    int seg_ = (n0_ >= 320) ? 2 : (n0_ >= 256) ? 1 : 0;
    const ushort* Aseg = t1 + seg_ * 256;
    GEMM_CORE_LDA(Aseg, Bt, 256, 768)

    float bsum = 0.f;
    float* outp = nullptr;
    int a_ = 0, s_ = 0, S_ = 1;
    if (seg_ == 0) {
        if (n < 240) { bsum = cb[n]; a_ = n / 80; s_ = n - a_ * 80; outp = cls_out; S_ = 80; }
    } else if (seg_ == 1) {
        int c = n - 256;
        if (c < 12) { bsum = bb[c]; a_ = c >> 2; s_ = c & 3; outp = box_out; S_ = 4; }
    } else {
        int c = n - 320;
        if (c < 3) { bsum = ob[c]; a_ = c; s_ = 0; outp = obj_out; S_ = 1; }
    }
    if (outp) {
        #pragma unroll
        for (int r = 0; r < 16; r++) {
            int row = (r & 3) + 8 * (r >> 2) + 4 * lg;
            int m = m0 + wm * 32 + row;
            int b = m / NP, hw = m - b * NP;
            outp[((size_t)(b * NA + a_) * NP + hw) * S_ + s_] = acc[r] + bsum;
        }
    }
}

// ---------------------------------------------------------------------------
// MFMA bf16 flash attention (R11 form — best measured). 32x32 shape,
// in-register softmax, 64 q/wave, split-KV x5, 1-deep register prefetch.
// ---------------------------------------------------------------------------
__global__ __launch_bounds__(320) void attn_mfma_kernel(
        const ushort* __restrict__ q, const ushort* __restrict__ k,
        const ushort* __restrict__ vt, ushort* __restrict__ o)
{
    __shared__ float mrg[5][64][36];    // [wave][lane][otA16,lA,pad, otB16,lB,pad]
    int lane = threadIdx.x & 63;
    int wid  = threadIdx.x >> 6;        // 0..4
    int qq   = lane & 31;               // query within tile
    int hi   = lane >> 5;               // lane half
    int h = blockIdx.y, b = blockIdx.z;
    int q0 = blockIdx.x * 64;
    int ks = wid * 320;                 // this wave's key range (320 keys)

    const size_t tq = (size_t)(b * NP + q0 + qq) * DD + h * HDD;
    bf16x8_t qfA1 = *(const bf16x8_t*)(q + tq + hi * 8);
    bf16x8_t qfA2 = *(const bf16x8_t*)(q + tq + 16 + hi * 8);
    bf16x8_t qfB1 = *(const bf16x8_t*)(q + tq + (size_t)32 * DD + hi * 8);
    bf16x8_t qfB2 = *(const bf16x8_t*)(q + tq + (size_t)32 * DD + 16 + hi * 8);

    const ushort* kp = k + (size_t)(b * NP + qq) * DD + h * HDD + hi * 8;
    const ushort* vp = vt + ((size_t)(b * NHH + h) * HDD + qq) * NP + hi * 8;

    float lsumA = 0.f, lsumB = 0.f;
    f32x16_t otA = {};                  // O^T[d][q]: q=lane&31, d=(r&3)+8*(r>>2)+4*hi
    f32x16_t otB = {};

    // prefetch tile 0
    bf16x8_t kf1 = *(const bf16x8_t*)(kp + (size_t)ks * DD);
    bf16x8_t kf2 = *(const bf16x8_t*)(kp + (size_t)ks * DD + 16);
    bf16x8_t vf1 = *(const bf16x8_t*)(vp + ks);
    bf16x8_t vf2 = *(const bf16x8_t*)(vp + ks + 16);

    for (int it = 0; it < 10; it++) {
        int kn = (it < 9) ? (ks + (it + 1) * 32) : ks;
        bf16x8_t nkf1 = *(const bf16x8_t*)(kp + (size_t)kn * DD);
        bf16x8_t nkf2 = *(const bf16x8_t*)(kp + (size_t)kn * DD + 16);
        bf16x8_t nvf1 = *(const bf16x8_t*)(vp + kn);
        bf16x8_t nvf2 = *(const bf16x8_t*)(vp + kn + 16);

        f32x16_t z = {};
        // --- q-tile A: QK^T
        f32x16_t sA = __builtin_amdgcn_mfma_f32_32x32x16_bf16(kf1, qfA1, z, 0, 0, 0);
        sA = __builtin_amdgcn_mfma_f32_32x32x16_bf16(kf2, qfA2, sA, 0, 0, 0);
        // --- q-tile B: QK^T (independent chain)
        f32x16_t sB = __builtin_amdgcn_mfma_f32_32x32x16_bf16(kf1, qfB1, z, 0, 0, 0);
        sB = __builtin_amdgcn_mfma_f32_32x32x16_bf16(kf2, qfB2, sB, 0, 0, 0);

        float pA[16], pB[16];
        #pragma unroll
        for (int r = 0; r < 16; r++) pA[r] = __builtin_amdgcn_exp2f(sA[r]);
        #pragma unroll
        for (int r = 0; r < 16; r++) pB[r] = __builtin_amdgcn_exp2f(sB[r]);
        lsumA += (((pA[0] + pA[1]) + (pA[2] + pA[3])) + ((pA[4] + pA[5]) + (pA[6] + pA[7])))
               + (((pA[8] + pA[9]) + (pA[10] + pA[11])) + ((pA[12] + pA[13]) + (pA[14] + pA[15])));
        lsumB += (((pB[0] + pB[1]) + (pB[2] + pB[3])) + ((pB[4] + pB[5]) + (pB[6] + pB[7])))
               + (((pB[8] + pB[9]) + (pB[10] + pB[11])) + ((pB[12] + pB[13]) + (pB[14] + pB[15])));

        unsigned int a0 = cvt_pk_bf16(pA[0],  pA[1]);
        unsigned int a1 = cvt_pk_bf16(pA[2],  pA[3]);
        unsigned int a2 = cvt_pk_bf16(pA[4],  pA[5]);
        unsigned int a3 = cvt_pk_bf16(pA[6],  pA[7]);
        unsigned int a4 = cvt_pk_bf16(pA[8],  pA[9]);
        unsigned int a5 = cvt_pk_bf16(pA[10], pA[11]);
        unsigned int a6 = cvt_pk_bf16(pA[12], pA[13]);
        unsigned int a7 = cvt_pk_bf16(pA[14], pA[15]);
        swap32(a2, a0); swap32(a3, a1); swap32(a6, a4); swap32(a7, a5);
        bf16x8_t pfA1 = pack4(a0, a1, a2, a3);
        bf16x8_t pfA2 = pack4(a4, a5, a6, a7);

        unsigned int b0 = cvt_pk_bf16(pB[0],  pB[1]);
        unsigned int b1 = cvt_pk_bf16(pB[2],  pB[3]);
        unsigned int b2 = cvt_pk_bf16(pB[4],  pB[5]);
        unsigned int b3 = cvt_pk_bf16(pB[6],  pB[7]);
        unsigned int b4 = cvt_pk_bf16(pB[8],  pB[9]);
        unsigned int b5 = cvt_pk_bf16(pB[10], pB[11]);
        unsigned int b6 = cvt_pk_bf16(pB[12], pB[13]);
        unsigned int b7 = cvt_pk_bf16(pB[14], pB[15]);
        swap32(b2, b0); swap32(b3, b1); swap32(b6, b4); swap32(b7, b5);
        bf16x8_t pfB1 = pack4(b0, b1, b2, b3);
        bf16x8_t pfB2 = pack4(b4, b5, b6, b7);

        // --- PV for both tiles (independent accumulator chains)
        otA = __builtin_amdgcn_mfma_f32_32x32x16_bf16(vf1, pfA1, otA, 0, 0, 0);
        otB = __builtin_amdgcn_mfma_f32_32x32x16_bf16(vf1, pfB1, otB, 0, 0, 0);
        otA = __builtin_amdgcn_mfma_f32_32x32x16_bf16(vf2, pfA2, otA, 0, 0, 0);
        otB = __builtin_amdgcn_mfma_f32_32x32x16_bf16(vf2, pfB2, otB, 0, 0, 0);

        kf1 = nkf1; kf2 = nkf2; vf1 = nvf1; vf2 = nvf2;
    }

    // lane-half reduce (lanes l and l^32 share query q)
    lsumA += __shfl_xor(lsumA, 32, 64);
    lsumB += __shfl_xor(lsumB, 32, 64);

    // merge the 5 split-KV partials through LDS
    #pragma unroll
    for (int r = 0; r < 16; r++) mrg[wid][lane][r] = otA[r];
    mrg[wid][lane][16] = lsumA;
    #pragma unroll
    for (int r = 0; r < 16; r++) mrg[wid][lane][18 + r] = otB[r];
    mrg[wid][lane][34] = lsumB;
    __syncthreads();

    if (wid < 2) {                       // wave 0 -> tile A, wave 1 -> tile B
        int off = wid * 18;
        float ov[16] = {};
        float L = 0.f;
        #pragma unroll
        for (int w = 0; w < 5; w++) {
            #pragma unroll
            for (int r = 0; r < 16; r++) ov[r] += mrg[w][lane][off + r];
            L += mrg[w][lane][off + 16];
        }
        float inv = 1.f / L;
        size_t tqo = tq + (size_t)wid * 32 * DD;
        #pragma unroll
        for (int i = 0; i < 4; i++) {
            ushort4 s4 = make_ushort4(f2bf(ov[4 * i + 0] * inv), f2bf(ov[4 * i + 1] * inv),
                                      f2bf(ov[4 * i + 2] * inv), f2bf(ov[4 * i + 3] * inv));
            *(ushort4*)(o + tqo + 8 * i + 4 * hi) = s4;
        }
    }
}

// ---------------------------------------------------------------------------
static inline void launch_gemm(const ushort* A, const ushort* Bt, const float* bias,
                               const float* bias2, const float* res, float* Cf,
                               ushort* Cbf, int M, int N, int K, int relu,
                               hipStream_t s) {
    dim3 g(N / 64, M / 64), b(256);
    hipLaunchKernelGGL(gemm_mfma_kernel, g, b, 0, s,
                       A, Bt, bias, bias2, res, Cf, Cbf, M, N, K, relu);
}

extern "C" void kernel_launch(void* const* d_in, const int* in_sizes, int n_in,
                              void* d_out, int out_size, void* d_ws, size_t ws_size,
                              hipStream_t stream) {
    const float* x      = (const float*)d_in[0];
    const float* conv_w = (const float*)d_in[1];
    const float* conv_b = (const float*)d_in[2];
    const float* pos    = (const float*)d_in[3];
    const float* qw     = (const float*)d_in[4];
    const float* qb     = (const float*)d_in[5];
    const float* kw     = (const float*)d_in[6];
    const float* kb     = (const float*)d_in[7];
    const float* vw     = (const float*)d_in[8];
    const float* vb     = (const float*)d_in[9];
    const float* pw     = (const float*)d_in[10];
    const float* pb     = (const float*)d_in[11];
    const float* ln1s   = (const float*)d_in[12];
    const float* ln1b   = (const float*)d_in[13];
    const float* ln2s   = (const float*)d_in[14];
    const float* ln2b   = (const float*)d_in[15];
    const float* f1w    = (const float*)d_in[16];
    const float* f1b    = (const float*)d_in[17];
    const float* f2w    = (const float*)d_in[18];
    const float* f2b    = (const float*)d_in[19];
    const float* cls_w1 = (const float*)d_in[20];
    const float* cls_b1 = (const float*)d_in[21];
    const float* cls_w2 = (const float*)d_in[22];
    const float* cls_b2 = (const float*)d_in[23];
    const float* box_w1 = (const float*)d_in[24];
    const float* box_b1 = (const float*)d_in[25];
    const float* box_w2 = (const float*)d_in[26];
    const float* box_b2 = (const float*)d_in[27];
    const float* obj_w1 = (const float*)d_in[28];
    const float* obj_b1 = (const float*)d_in[29];
    const float* obj_w2 = (const float*)d_in[30];
    const float* obj_b2 = (const float*)d_in[31];

    float* out = (float*)d_out;
    const size_t TD = (size_t)TT * DD;   // 1,638,400

    // byte-based workspace layout
    char* p = (char*)d_ws;
    auto alloc = [&](size_t bytes) { char* r = p; p += (bytes + 255) & ~(size_t)255; return r; };
    float*  h    = (float*) alloc(TD * 4);
    ushort* qB   = (ushort*)alloc(TD * 2);
    ushort* kB   = (ushort*)alloc(TD * 2);
    ushort* Vt   = (ushort*)alloc(TD * 2);   // [B][NH][HD][NP]
    ushort* oB   = (ushort*)alloc(TD * 2);
    ushort* hbf  = (ushort*)alloc(TD * 2);
    ushort* ffn  = (ushort*)alloc((size_t)TT * FF * 2);
    ushort* xT   = (ushort*)alloc((size_t)TT * CIN * 2);
    ushort* wT   = (ushort*)alloc((size_t)(2949120 + 98304) * 2);
    ushort* t1   = ffn;                  // reuse ffn region after transformer ([T][768])

    // transposed-weight layout (ushort offsets into wT):
    ushort* convT  = wT;
    ushort* qkvT   = wT + 131072;
    ushort* pwT    = wT + 524288;
    ushort* f1wT   = wT + 655360;
    ushort* f2wT   = wT + 1703936;
    ushort* headT  = wT + 2752512;
    ushort* head2T = wT + 2949120;       // [384][256]

    // Q pre-scale: (1/sqrt(HD)) * log2(e) -> scores ready for exp2
    const float QSCALE = 0.17677669529663687f * 1.4426950408889634f;

    // 0) weight prep (transpose + scale + bf16)
    WPrep wp;
    int total_tiles = 0;
    auto setd = [&](int i, const float* src, ushort* dst, int R, int C, float sc) {
        wp.d[i] = {src, dst, R, C, (R / 32) * (C / 32), sc};
        total_tiles += wp.d[i].ntiles;
    };
    setd(0,  conv_w, convT, CIN, DD, 1.f);
    setd(1,  qw,            qkvT,                    DD, DD, QSCALE);
    setd(2,  kw,            qkvT + 65536,            DD, DD, 1.f);
    setd(3,  vw,            qkvT + 131072,           DD, DD, 1.f);
    setd(4,  qw + DD * DD,  qkvT + 196608,           DD, DD, QSCALE);
    setd(5,  kw + DD * DD,  qkvT + 196608 + 65536,   DD, DD, 1.f);
    setd(6,  vw + DD * DD,  qkvT + 196608 + 131072,  DD, DD, 1.f);
    setd(7,  pw,            pwT,            DD, DD, 1.f);
    setd(8,  pw + DD * DD,  pwT + DD * DD,  DD, DD, 1.f);
    setd(9,  f1w,           f1wT,           DD, FF, 1.f);
    setd(10, f1w + DD * FF, f1wT + DD * FF, DD, FF, 1.f);
    setd(11, f2w,           f2wT,           FF, DD, 1.f);
    setd(12, f2w + FF * DD, f2wT + FF * DD, FF, DD, 1.f);
    setd(13, cls_w1, headT,          DD, DD, 1.f);
    setd(14, box_w1, headT + 65536,  DD, DD, 1.f);
    setd(15, obj_w1, headT + 131072, DD, DD, 1.f);
    hipLaunchKernelGGL(wprep_kernel, dim3(total_tiles), dim3(32, 8), 0, stream, wp);
    hipLaunchKernelGGL(head2_wprep_kernel, dim3(384), dim3(256), 0, stream,
                       cls_w2, box_w2, obj_w2, head2T);

    // 1) x transpose -> [T, CIN] bf16
    hipLaunchKernelGGL(transpose_x_kernel, dim3(CIN / 32, NP / 32, BB), dim3(32, 8),
                       0, stream, x, xT);

    // 2) conv 1x1 projection + conv_b + pos -> h [T, D] f32
    launch_gemm(xT, convT, conv_b, pos, nullptr, h, nullptr, TT, DD, CIN, 0, stream);

    // 3) transformer layers (LN fused into QKV / FFN1 A-staging)
    for (int i = 0; i < 2; i++) {
        hipLaunchKernelGGL(gemm_ln_qkv_kernel, dim3(768 / 64, TT / 64), dim3(256), 0, stream,
                           h, qkvT + (size_t)i * 196608, ln1s + i * DD, ln1b + i * DD,
                           qb + i * DD, kb + i * DD, vb + i * DD, qB, kB, Vt, QSCALE);

        hipLaunchKernelGGL(attn_mfma_kernel, dim3(NP / 64, NHH, BB), dim3(320), 0, stream,
                           qB, kB, Vt, oB);

        launch_gemm(oB, pwT + (size_t)i * DD * DD, pb + i * DD, nullptr, h, h, nullptr,
                    TT, DD, DD, 0, stream);

        hipLaunchKernelGGL(gemm_ln_ffn1_kernel, dim3(FF / 64, TT / 64), dim3(256), 0, stream,
                           h, f1wT + (size_t)i * DD * FF, ln2s + i * DD, ln2b + i * DD,
                           f1b + i * FF, ffn);

        launch_gemm(ffn, f2wT + (size_t)i * FF * DD, f2b + i * DD, nullptr, h,
                    (i == 0) ? h : nullptr, (i == 1) ? hbf : nullptr,
                    TT, DD, FF, 0, stream);
    }

    // 4) heads: fused layer-1 GEMM (N=768) -> t1 [T][768],
    //    then ONE fused layer-2 MFMA GEMM (N=384) scattering into outputs.
    hipLaunchKernelGGL(gemm_head1_kernel, dim3(768 / 64, TT / 64), dim3(256), 0, stream,
                       hbf, headT, cls_b1, box_b1, obj_b1, t1);

    float* cls_out = out;
    float* box_out = out + (size_t)BB * NA * NP * NC;
    float* obj_out = box_out + (size_t)BB * NA * NP * 4;

    hipLaunchKernelGGL(gemm_head2_kernel, dim3(384 / 64, TT / 64), dim3(256), 0, stream,
                       t1, head2T, cls_b2, box_b2, obj_b2, cls_out, box_out, obj_out);
}

// Round 14
// 257.284 us; speedup vs baseline: 1.9073x; 1.9073x over previous
//
#include <hip/hip_runtime.h>
#include <math.h>

// Problem constants
#define BB   4
#define CIN  512
#define DD   256
#define NP   1600      // tokens per image (40*40)
#define TT   (BB*NP)   // 6400 total tokens
#define FF   2048
#define NHH  8
#define HDD  32
#define NA   3
#define NC   80

typedef __attribute__((ext_vector_type(8))) short bf16x8_t;
typedef __attribute__((ext_vector_type(4))) float f32x4_t;
typedef __attribute__((ext_vector_type(16))) float f32x16_t;

static __device__ __forceinline__ ushort f2bf(float f) {
    unsigned int u = __float_as_uint(f);
    u += 0x7FFF + ((u >> 16) & 1);          // round-to-nearest-even
    return (ushort)(u >> 16);
}
static __device__ __forceinline__ float bf2f(ushort u) {
    return __uint_as_float((unsigned int)u << 16);
}
// pack 2 f32 -> 1 u32 of 2 bf16 (RNE), single v_cvt_pk_bf16_f32
static __device__ __forceinline__ unsigned int cvt_pk_bf16(float lo, float hi) {
    unsigned int r;
    asm("v_cvt_pk_bf16_f32 %0, %1, %2" : "=v"(r) : "v"(lo), "v"(hi));
    return r;
}
// exchange a.lanes[half] <-> b.lanes[other half]
static __device__ __forceinline__ void swap32(unsigned int& a, unsigned int& b) {
    asm("v_permlane32_swap_b32 %0, %1" : "+v"(a), "+v"(b));
}
static __device__ __forceinline__ bf16x8_t pack4(unsigned int a, unsigned int b,
                                                 unsigned int c, unsigned int d) {
    union { uint4 u; bf16x8_t v; } t;
    t.u = make_uint4(a, b, c, d);
    return t.v;
}

// ---------------------------------------------------------------------------
// Weight prep: batched transpose + scale + fp32->bf16.
// src [R][C] f32 -> dst [C][R] bf16 (dst = src^T * scale)
// ---------------------------------------------------------------------------
struct WDesc { const float* src; ushort* dst; int R; int C; int ntiles; float scale; };
struct WPrep { WDesc d[16]; };

__global__ __launch_bounds__(256) void wprep_kernel(WPrep p) {
    __shared__ float tile[32][33];
    int t = blockIdx.x;
    int i = 0;
    while (t >= p.d[i].ntiles) { t -= p.d[i].ntiles; i++; }
    const float* src = p.d[i].src;
    ushort* dst = p.d[i].dst;
    int R = p.d[i].R, C = p.d[i].C;
    float sc = p.d[i].scale;
    int tC = C >> 5;
    int r0 = (t / tC) * 32, c0 = (t % tC) * 32;
    int tx = threadIdx.x, ty = threadIdx.y;
    #pragma unroll
    for (int j = 0; j < 32; j += 8)
        tile[ty + j][tx] = src[(size_t)(r0 + ty + j) * C + (c0 + tx)];
    __syncthreads();
    #pragma unroll
    for (int j = 0; j < 32; j += 8)
        dst[(size_t)(c0 + ty + j) * R + (r0 + tx)] = f2bf(tile[tx][ty + j] * sc);
}

// ---------------------------------------------------------------------------
// Head-2 combined weight prep: build Bt [384][256] bf16 (cls|pad|box|pad|obj)
// ---------------------------------------------------------------------------
__global__ __launch_bounds__(256) void head2_wprep_kernel(
        const float* __restrict__ cls_w2, const float* __restrict__ box_w2,
        const float* __restrict__ obj_w2, ushort* __restrict__ dst)
{
    int nrow = blockIdx.x;      // 0..383
    int k = threadIdx.x;        // 0..255
    float v = 0.f;
    if (nrow < 240)                      v = cls_w2[k * 240 + nrow];
    else if (nrow >= 256 && nrow < 268)  v = box_w2[k * 12 + (nrow - 256)];
    else if (nrow >= 320 && nrow < 323)  v = obj_w2[k * 3 + (nrow - 320)];
    dst[(size_t)nrow * 256 + k] = f2bf(v);
}

// ---------------------------------------------------------------------------
// Transpose x [B][CIN][NP] f32 -> xT [T][CIN] bf16
// ---------------------------------------------------------------------------
__global__ void transpose_x_kernel(const float* __restrict__ x, ushort* __restrict__ xT) {
    __shared__ float tile[32][33];
    int b  = blockIdx.z;
    int c0 = blockIdx.x * 32;
    int n0 = blockIdx.y * 32;
    int tx = threadIdx.x, ty = threadIdx.y;
    #pragma unroll
    for (int j = 0; j < 32; j += 8) {
        tile[ty + j][tx] = x[b * CIN * NP + (c0 + ty + j) * NP + (n0 + tx)];
    }
    __syncthreads();
    #pragma unroll
    for (int j = 0; j < 32; j += 8) {
        xT[(size_t)(b * NP + n0 + ty + j) * CIN + (c0 + tx)] = f2bf(tile[tx][ty + j]);
    }
}

// ---------------------------------------------------------------------------
// Shared GEMM core: stages 64x64 A/B tiles, accumulates one 32x32 fragment
// per wave (4 waves). K_ multiple of 64; LDA_ is A's row stride.
// ---------------------------------------------------------------------------
#define GEMM_CORE_LDA(A_, Bt_, K_, LDA_)                                         \
    __shared__ ushort As[64][72];                                                \
    __shared__ ushort Bs[64][72];                                                \
    int tid  = threadIdx.x;                                                      \
    int lane = tid & 63, wid = tid >> 6;                                         \
    int wm = wid >> 1, wn = wid & 1;                                             \
    int m0 = blockIdx.y * 64, n0 = blockIdx.x * 64;                              \
    int ln31 = lane & 31, lg = lane >> 5;                                        \
    int srow = tid >> 2;                                                         \
    int scol = (tid & 3) * 16;                                                   \
    const ushort* ag = (A_)  + (size_t)(m0 + srow) * (LDA_) + scol;              \
    const ushort* bg = (Bt_) + (size_t)(n0 + srow) * (K_) + scol;                \
    f32x16_t acc = {};                                                           \
    for (int k0 = 0; k0 < (K_); k0 += 64) {                                      \
        uint4 av0 = *(const uint4*)(ag + k0);                                    \
        uint4 av1 = *(const uint4*)(ag + k0 + 8);                                \
        uint4 bv0 = *(const uint4*)(bg + k0);                                    \
        uint4 bv1 = *(const uint4*)(bg + k0 + 8);                                \
        *(uint4*)&As[srow][scol]     = av0;                                      \
        *(uint4*)&As[srow][scol + 8] = av1;                                      \
        *(uint4*)&Bs[srow][scol]     = bv0;                                      \
        *(uint4*)&Bs[srow][scol + 8] = bv1;                                      \
        __syncthreads();                                                         \
        _Pragma("unroll")                                                        \
        for (int kc = 0; kc < 4; kc++) {                                         \
            bf16x8_t af = *(const bf16x8_t*)&As[wm * 32 + ln31][kc * 16 + lg * 8]; \
            bf16x8_t bf = *(const bf16x8_t*)&Bs[wn * 32 + ln31][kc * 16 + lg * 8]; \
            acc = __builtin_amdgcn_mfma_f32_32x32x16_bf16(af, bf, acc, 0, 0, 0); \
        }                                                                        \
        __syncthreads();                                                         \
    }                                                                            \
    int n = n0 + wn * 32 + ln31;

#define GEMM_CORE(A_, Bt_, K_) GEMM_CORE_LDA(A_, Bt_, K_, K_)

// ---------------------------------------------------------------------------
// Generic MFMA bf16 GEMM: + bias (+bias2) (+residual f32), opt ReLU.
// ---------------------------------------------------------------------------
__global__ __launch_bounds__(256) void gemm_mfma_kernel(
        const ushort* __restrict__ A, const ushort* __restrict__ Bt,
        const float* __restrict__ bias, const float* __restrict__ bias2,
        const float* __restrict__ residual, float* __restrict__ Cf,
        ushort* __restrict__ Cbf, int M, int N, int K, int do_relu)
{
    GEMM_CORE(A, Bt, K)
    float bsum = bias[n] + (bias2 ? bias2[n] : 0.f);
    #pragma unroll
    for (int r = 0; r < 16; r++) {
        int row = (r & 3) + 8 * (r >> 2) + 4 * lg;
        int m = m0 + wm * 32 + row;
        float v = acc[r] + bsum;
        if (do_relu) v = fmaxf(v, 0.f);
        if (residual) v += residual[(size_t)m * N + n];
        if (Cf)  Cf [(size_t)m * N + n] = v;
        if (Cbf) Cbf[(size_t)m * N + n] = f2bf(v);
    }
}

// ---------------------------------------------------------------------------
// Fused QKV GEMM: A=y [T][256], Bt=qkvT [768][256]. Segment by n.
// ---------------------------------------------------------------------------
__global__ __launch_bounds__(256) void gemm_qkv_kernel(
        const ushort* __restrict__ A, const ushort* __restrict__ Bt,
        const float* __restrict__ qb, const float* __restrict__ kb,
        const float* __restrict__ vb, ushort* __restrict__ q_out,
        ushort* __restrict__ k_out, ushort* __restrict__ vt_out, float qscale)
{
    GEMM_CORE(A, Bt, DD)
    int seg = n >> 8;        // block-uniform (N-tile 64 within one segment)
    int c   = n & 255;
    if (seg == 0) {
        float bsum = qb[c] * qscale;
        #pragma unroll
        for (int r = 0; r < 16; r++) {
            int row = (r & 3) + 8 * (r >> 2) + 4 * lg;
            q_out[(size_t)(m0 + wm * 32 + row) * DD + c] = f2bf(acc[r] + bsum);
        }
    } else if (seg == 1) {
        float bsum = kb[c];
        #pragma unroll
        for (int r = 0; r < 16; r++) {
            int row = (r & 3) + 8 * (r >> 2) + 4 * lg;
            k_out[(size_t)(m0 + wm * 32 + row) * DD + c] = f2bf(acc[r] + bsum);
        }
    } else {
        float bsum = vb[c];
        int b = m0 / NP;
        int nn0 = m0 - b * NP + wm * 32 + 4 * lg;
        int hh = c >> 5, d = c & 31;
        ushort* vt = vt_out + ((size_t)(b * NHH + hh) * HDD + d) * NP + nn0;
        #pragma unroll
        for (int qq = 0; qq < 4; qq++) {
            ushort4 w4 = make_ushort4(f2bf(acc[qq * 4 + 0] + bsum), f2bf(acc[qq * 4 + 1] + bsum),
                                      f2bf(acc[qq * 4 + 2] + bsum), f2bf(acc[qq * 4 + 3] + bsum));
            *(ushort4*)(vt + 8 * qq) = w4;
        }
    }
}

// ---------------------------------------------------------------------------
// Fused heads layer-1 GEMM -> t1 [T][768] bf16 (ReLU)
// ---------------------------------------------------------------------------
__global__ __launch_bounds__(256) void gemm_head1_kernel(
        const ushort* __restrict__ A, const ushort* __restrict__ Bt,
        const float* __restrict__ b0, const float* __restrict__ b1,
        const float* __restrict__ b2, ushort* __restrict__ t1)
{
    GEMM_CORE(A, Bt, DD)
    int seg = n >> 8;
    int c   = n & 255;
    float bsum = (seg == 0) ? b0[c] : (seg == 1) ? b1[c] : b2[c];
    #pragma unroll
    for (int r = 0; r < 16; r++) {
        int row = (r & 3) + 8 * (r >> 2) + 4 * lg;
        float v = fmaxf(acc[r] + bsum, 0.f);
        t1[(size_t)(m0 + wm * 32 + row) * 768 + n] = f2bf(v);
    }
}

// ---------------------------------------------------------------------------
// Fused heads layer-2 GEMM: N=384 combined; scatters into [B,NA,H,W,S] outs.
// ---------------------------------------------------------------------------
__global__ __launch_bounds__(256) void gemm_head2_kernel(
        const ushort* __restrict__ t1, const ushort* __restrict__ Bt,
        const float* __restrict__ cb, const float* __restrict__ bb,
        const float* __restrict__ ob, float* __restrict__ cls_out,
        float* __restrict__ box_out, float* __restrict__ obj_out)
{
    int n0_ = blockIdx.x * 64;
    int seg_ = (n0_ >= 320) ? 2 : (n0_ >= 256) ? 1 : 0;
    const ushort* Aseg = t1 + seg_ * 256;
    GEMM_CORE_LDA(Aseg, Bt, 256, 768)

    float bsum = 0.f;
    float* outp = nullptr;
    int a_ = 0, s_ = 0, S_ = 1;
    if (seg_ == 0) {
        if (n < 240) { bsum = cb[n]; a_ = n / 80; s_ = n - a_ * 80; outp = cls_out; S_ = 80; }
    } else if (seg_ == 1) {
        int c = n - 256;
        if (c < 12) { bsum = bb[c]; a_ = c >> 2; s_ = c & 3; outp = box_out; S_ = 4; }
    } else {
        int c = n - 320;
        if (c < 3) { bsum = ob[c]; a_ = c; s_ = 0; outp = obj_out; S_ = 1; }
    }
    if (outp) {
        #pragma unroll
        for (int r = 0; r < 16; r++) {
            int row = (r & 3) + 8 * (r >> 2) + 4 * lg;
            int m = m0 + wm * 32 + row;
            int b = m / NP, hw = m - b * NP;
            outp[((size_t)(b * NA + a_) * NP + hw) * S_ + s_] = acc[r] + bsum;
        }
    }
}

// ---------------------------------------------------------------------------
// LayerNorm: one block (256 threads) per row of [T, 256]; f32 in, bf16 out
// ---------------------------------------------------------------------------
__global__ __launch_bounds__(256) void ln_kernel(
        const float* __restrict__ x, const float* __restrict__ s,
        const float* __restrict__ b, ushort* __restrict__ y)
{
    int row = blockIdx.x;
    int t = threadIdx.x;
    float v = x[(size_t)row * DD + t];
    float s1 = v, s2 = v * v;
    #pragma unroll
    for (int m = 32; m >= 1; m >>= 1) {
        s1 += __shfl_xor(s1, m, 64);
        s2 += __shfl_xor(s2, m, 64);
    }
    __shared__ float w1[4], w2[4];
    int lane = t & 63, wid = t >> 6;
    if (lane == 0) { w1[wid] = s1; w2[wid] = s2; }
    __syncthreads();
    float S1 = w1[0] + w1[1] + w1[2] + w1[3];
    float S2 = w2[0] + w2[1] + w2[2] + w2[3];
    float mean = S1 * (1.f / DD);
    float var  = S2 * (1.f / DD) - mean * mean;
    float inv  = rsqrtf(var + 1e-5f);
    y[(size_t)row * DD + t] = f2bf((v - mean) * inv * s[t] + b[t]);
}

// ---------------------------------------------------------------------------
// MFMA bf16 flash attention, 32x32 shape, in-register softmax, 64 q/wave.
// Block = 5 waves (split-KV x5, 320 keys each); each wave computes TWO 32-q
// tiles per loaded K/V tile -> 2x arithmetic intensity + 2 independent
// softmax chains (ILP). Partials merged once through LDS.
// ---------------------------------------------------------------------------
__global__ __launch_bounds__(320) void attn_mfma_kernel(
        const ushort* __restrict__ q, const ushort* __restrict__ k,
        const ushort* __restrict__ vt, ushort* __restrict__ o)
{
    __shared__ float mrg[5][64][36];    // [wave][lane][otA16,lA,pad, otB16,lB,pad]
    int lane = threadIdx.x & 63;
    int wid  = threadIdx.x >> 6;        // 0..4
    int qq   = lane & 31;               // query within tile
    int hi   = lane >> 5;               // lane half
    int h = blockIdx.y, b = blockIdx.z;
    int q0 = blockIdx.x * 64;
    int ks = wid * 320;                 // this wave's key range (320 keys)

    const size_t tq = (size_t)(b * NP + q0 + qq) * DD + h * HDD;
    bf16x8_t qfA1 = *(const bf16x8_t*)(q + tq + hi * 8);
    bf16x8_t qfA2 = *(const bf16x8_t*)(q + tq + 16 + hi * 8);
    bf16x8_t qfB1 = *(const bf16x8_t*)(q + tq + (size_t)32 * DD + hi * 8);
    bf16x8_t qfB2 = *(const bf16x8_t*)(q + tq + (size_t)32 * DD + 16 + hi * 8);

    const ushort* kp = k + (size_t)(b * NP + qq) * DD + h * HDD + hi * 8;
    const ushort* vp = vt + ((size_t)(b * NHH + h) * HDD + qq) * NP + hi * 8;

    float lsumA = 0.f, lsumB = 0.f;
    f32x16_t otA = {};                  // O^T[d][q]: q=lane&31, d=(r&3)+8*(r>>2)+4*hi
    f32x16_t otB = {};

    // prefetch tile 0
    bf16x8_t kf1 = *(const bf16x8_t*)(kp + (size_t)ks * DD);
    bf16x8_t kf2 = *(const bf16x8_t*)(kp + (size_t)ks * DD + 16);
    bf16x8_t vf1 = *(const bf16x8_t*)(vp + ks);
    bf16x8_t vf2 = *(const bf16x8_t*)(vp + ks + 16);

    for (int it = 0; it < 10; it++) {
        int kn = (it < 9) ? (ks + (it + 1) * 32) : ks;
        bf16x8_t nkf1 = *(const bf16x8_t*)(kp + (size_t)kn * DD);
        bf16x8_t nkf2 = *(const bf16x8_t*)(kp + (size_t)kn * DD + 16);
        bf16x8_t nvf1 = *(const bf16x8_t*)(vp + kn);
        bf16x8_t nvf2 = *(const bf16x8_t*)(vp + kn + 16);

        f32x16_t z = {};
        // --- q-tile A: QK^T
        f32x16_t sA = __builtin_amdgcn_mfma_f32_32x32x16_bf16(kf1, qfA1, z, 0, 0, 0);
        sA = __builtin_amdgcn_mfma_f32_32x32x16_bf16(kf2, qfA2, sA, 0, 0, 0);
        // --- q-tile B: QK^T (independent chain, fills A's latency)
        f32x16_t sB = __builtin_amdgcn_mfma_f32_32x32x16_bf16(kf1, qfB1, z, 0, 0, 0);
        sB = __builtin_amdgcn_mfma_f32_32x32x16_bf16(kf2, qfB2, sB, 0, 0, 0);

        float pA[16], pB[16];
        #pragma unroll
        for (int r = 0; r < 16; r++) pA[r] = __builtin_amdgcn_exp2f(sA[r]);
        #pragma unroll
        for (int r = 0; r < 16; r++) pB[r] = __builtin_amdgcn_exp2f(sB[r]);
        lsumA += (((pA[0] + pA[1]) + (pA[2] + pA[3])) + ((pA[4] + pA[5]) + (pA[6] + pA[7])))
               + (((pA[8] + pA[9]) + (pA[10] + pA[11])) + ((pA[12] + pA[13]) + (pA[14] + pA[15])));
        lsumB += (((pB[0] + pB[1]) + (pB[2] + pB[3])) + ((pB[4] + pB[5]) + (pB[6] + pB[7])))
               + (((pB[8] + pB[9]) + (pB[10] + pB[11])) + ((pB[12] + pB[13]) + (pB[14] + pB[15])));

        unsigned int a0 = cvt_pk_bf16(pA[0],  pA[1]);
        unsigned int a1 = cvt_pk_bf16(pA[2],  pA[3]);
        unsigned int a2 = cvt_pk_bf16(pA[4],  pA[5]);
        unsigned int a3 = cvt_pk_bf16(pA[6],  pA[7]);
        unsigned int a4 = cvt_pk_bf16(pA[8],  pA[9]);
        unsigned int a5 = cvt_pk_bf16(pA[10], pA[11]);
        unsigned int a6 = cvt_pk_bf16(pA[12], pA[13]);
        unsigned int a7 = cvt_pk_bf16(pA[14], pA[15]);
        swap32(a2, a0); swap32(a3, a1); swap32(a6, a4); swap32(a7, a5);
        bf16x8_t pfA1 = pack4(a0, a1, a2, a3);
        bf16x8_t pfA2 = pack4(a4, a5, a6, a7);

        unsigned int b0 = cvt_pk_bf16(pB[0],  pB[1]);
        unsigned int b1 = cvt_pk_bf16(pB[2],  pB[3]);
        unsigned int b2 = cvt_pk_bf16(pB[4],  pB[5]);
        unsigned int b3 = cvt_pk_bf16(pB[6],  pB[7]);
        unsigned int b4 = cvt_pk_bf16(pB[8],  pB[9]);
        unsigned int b5 = cvt_pk_bf16(pB[10], pB[11]);
        unsigned int b6 = cvt_pk_bf16(pB[12], pB[13]);
        unsigned int b7 = cvt_pk_bf16(pB[14], pB[15]);
        swap32(b2, b0); swap32(b3, b1); swap32(b6, b4); swap32(b7, b5);
        bf16x8_t pfB1 = pack4(b0, b1, b2, b3);
        bf16x8_t pfB2 = pack4(b4, b5, b6, b7);

        // --- PV for both tiles (independent accumulator chains)
        otA = __builtin_amdgcn_mfma_f32_32x32x16_bf16(vf1, pfA1, otA, 0, 0, 0);
        otB = __builtin_amdgcn_mfma_f32_32x32x16_bf16(vf1, pfB1, otB, 0, 0, 0);
        otA = __builtin_amdgcn_mfma_f32_32x32x16_bf16(vf2, pfA2, otA, 0, 0, 0);
        otB = __builtin_amdgcn_mfma_f32_32x32x16_bf16(vf2, pfB2, otB, 0, 0, 0);

        kf1 = nkf1; kf2 = nkf2; vf1 = nvf1; vf2 = nvf2;
    }

    // lane-half reduce (lanes l and l^32 share query q)
    lsumA += __shfl_xor(lsumA, 32, 64);
    lsumB += __shfl_xor(lsumB, 32, 64);

    // merge the 5 split-KV partials through LDS
    #pragma unroll
    for (int r = 0; r < 16; r++) mrg[wid][lane][r] = otA[r];
    mrg[wid][lane][16] = lsumA;
    #pragma unroll
    for (int r = 0; r < 16; r++) mrg[wid][lane][18 + r] = otB[r];
    mrg[wid][lane][34] = lsumB;
    __syncthreads();

    if (wid < 2) {                       // wave 0 -> tile A, wave 1 -> tile B
        int off = wid * 18;
        float ov[16] = {};
        float L = 0.f;
        #pragma unroll
        for (int w = 0; w < 5; w++) {
            #pragma unroll
            for (int r = 0; r < 16; r++) ov[r] += mrg[w][lane][off + r];
            L += mrg[w][lane][off + 16];
        }
        float inv = 1.f / L;
        size_t tqo = tq + (size_t)wid * 32 * DD;
        // d runs: r=4i..4i+3 -> d = 8i + 4hi + (0..3)
        #pragma unroll
        for (int i = 0; i < 4; i++) {
            ushort4 s4 = make_ushort4(f2bf(ov[4 * i + 0] * inv), f2bf(ov[4 * i + 1] * inv),
                                      f2bf(ov[4 * i + 2] * inv), f2bf(ov[4 * i + 3] * inv));
            *(ushort4*)(o + tqo + 8 * i + 4 * hi) = s4;
        }
    }
}

// ---------------------------------------------------------------------------
static inline void launch_gemm(const ushort* A, const ushort* Bt, const float* bias,
                               const float* bias2, const float* res, float* Cf,
                               ushort* Cbf, int M, int N, int K, int relu,
                               hipStream_t s) {
    dim3 g(N / 64, M / 64), b(256);
    hipLaunchKernelGGL(gemm_mfma_kernel, g, b, 0, s,
                       A, Bt, bias, bias2, res, Cf, Cbf, M, N, K, relu);
}

extern "C" void kernel_launch(void* const* d_in, const int* in_sizes, int n_in,
                              void* d_out, int out_size, void* d_ws, size_t ws_size,
                              hipStream_t stream) {
    const float* x      = (const float*)d_in[0];
    const float* conv_w = (const float*)d_in[1];
    const float* conv_b = (const float*)d_in[2];
    const float* pos    = (const float*)d_in[3];
    const float* qw     = (const float*)d_in[4];
    const float* qb     = (const float*)d_in[5];
    const float* kw     = (const float*)d_in[6];
    const float* kb     = (const float*)d_in[7];
    const float* vw     = (const float*)d_in[8];
    const float* vb     = (const float*)d_in[9];
    const float* pw     = (const float*)d_in[10];
    const float* pb     = (const float*)d_in[11];
    const float* ln1s   = (const float*)d_in[12];
    const float* ln1b   = (const float*)d_in[13];
    const float* ln2s   = (const float*)d_in[14];
    const float* ln2b   = (const float*)d_in[15];
    const float* f1w    = (const float*)d_in[16];
    const float* f1b    = (const float*)d_in[17];
    const float* f2w    = (const float*)d_in[18];
    const float* f2b    = (const float*)d_in[19];
    const float* cls_w1 = (const float*)d_in[20];
    const float* cls_b1 = (const float*)d_in[21];
    const float* cls_w2 = (const float*)d_in[22];
    const float* cls_b2 = (const float*)d_in[23];
    const float* box_w1 = (const float*)d_in[24];
    const float* box_b1 = (const float*)d_in[25];
    const float* box_w2 = (const float*)d_in[26];
    const float* box_b2 = (const float*)d_in[27];
    const float* obj_w1 = (const float*)d_in[28];
    const float* obj_b1 = (const float*)d_in[29];
    const float* obj_w2 = (const float*)d_in[30];
    const float* obj_b2 = (const float*)d_in[31];

    float* out = (float*)d_out;
    const size_t TD = (size_t)TT * DD;   // 1,638,400

    // byte-based workspace layout
    char* p = (char*)d_ws;
    auto alloc = [&](size_t bytes) { char* r = p; p += (bytes + 255) & ~(size_t)255; return r; };
    float*  h    = (float*) alloc(TD * 4);
    ushort* y    = (ushort*)alloc(TD * 2);
    ushort* qB   = (ushort*)alloc(TD * 2);
    ushort* kB   = (ushort*)alloc(TD * 2);
    ushort* Vt   = (ushort*)alloc(TD * 2);   // [B][NH][HD][NP]
    ushort* oB   = (ushort*)alloc(TD * 2);
    ushort* hbf  = (ushort*)alloc(TD * 2);
    ushort* ffn  = (ushort*)alloc((size_t)TT * FF * 2);
    ushort* xT   = (ushort*)alloc((size_t)TT * CIN * 2);
    ushort* wT   = (ushort*)alloc((size_t)(2949120 + 98304) * 2);
    ushort* t1   = ffn;                  // reuse ffn region after transformer ([T][768])

    // transposed-weight layout (ushort offsets into wT):
    ushort* convT  = wT;
    ushort* qkvT   = wT + 131072;
    ushort* pwT    = wT + 524288;
    ushort* f1wT   = wT + 655360;
    ushort* f2wT   = wT + 1703936;
    ushort* headT  = wT + 2752512;
    ushort* head2T = wT + 2949120;       // [384][256]

    // Q pre-scale: (1/sqrt(HD)) * log2(e) -> scores ready for exp2
    const float QSCALE = 0.17677669529663687f * 1.4426950408889634f;

    // 0) weight prep (transpose + scale + bf16)
    WPrep wp;
    int total_tiles = 0;
    auto setd = [&](int i, const float* src, ushort* dst, int R, int C, float sc) {
        wp.d[i] = {src, dst, R, C, (R / 32) * (C / 32), sc};
        total_tiles += wp.d[i].ntiles;
    };
    setd(0,  conv_w, convT, CIN, DD, 1.f);
    setd(1,  qw,            qkvT,                    DD, DD, QSCALE);
    setd(2,  kw,            qkvT + 65536,            DD, DD, 1.f);
    setd(3,  vw,            qkvT + 131072,           DD, DD, 1.f);
    setd(4,  qw + DD * DD,  qkvT + 196608,           DD, DD, QSCALE);
    setd(5,  kw + DD * DD,  qkvT + 196608 + 65536,   DD, DD, 1.f);
    setd(6,  vw + DD * DD,  qkvT + 196608 + 131072,  DD, DD, 1.f);
    setd(7,  pw,            pwT,            DD, DD, 1.f);
    setd(8,  pw + DD * DD,  pwT + DD * DD,  DD, DD, 1.f);
    setd(9,  f1w,           f1wT,           DD, FF, 1.f);
    setd(10, f1w + DD * FF, f1wT + DD * FF, DD, FF, 1.f);
    setd(11, f2w,           f2wT,           FF, DD, 1.f);
    setd(12, f2w + FF * DD, f2wT + FF * DD, FF, DD, 1.f);
    setd(13, cls_w1, headT,          DD, DD, 1.f);
    setd(14, box_w1, headT + 65536,  DD, DD, 1.f);
    setd(15, obj_w1, headT + 131072, DD, DD, 1.f);
    hipLaunchKernelGGL(wprep_kernel, dim3(total_tiles), dim3(32, 8), 0, stream, wp);
    hipLaunchKernelGGL(head2_wprep_kernel, dim3(384), dim3(256), 0, stream,
                       cls_w2, box_w2, obj_w2, head2T);

    // 1) x transpose -> [T, CIN] bf16
    hipLaunchKernelGGL(transpose_x_kernel, dim3(CIN / 32, NP / 32, BB), dim3(32, 8),
                       0, stream, x, xT);

    // 2) conv 1x1 projection + conv_b + pos -> h [T, D] f32
    launch_gemm(xT, convT, conv_b, pos, nullptr, h, nullptr, TT, DD, CIN, 0, stream);

    // 3) transformer layers
    for (int i = 0; i < 2; i++) {
        hipLaunchKernelGGL(ln_kernel, dim3(TT), dim3(DD), 0, stream,
                           h, ln1s + i * DD, ln1b + i * DD, y);
        // fused QKV (N=768)
        hipLaunchKernelGGL(gemm_qkv_kernel, dim3(768 / 64, TT / 64), dim3(256), 0, stream,
                           y, qkvT + (size_t)i * 196608, qb + i * DD, kb + i * DD,
                           vb + i * DD, qB, kB, Vt, QSCALE);

        hipLaunchKernelGGL(attn_mfma_kernel, dim3(NP / 64, NHH, BB), dim3(320), 0, stream,
                           qB, kB, Vt, oB);

        launch_gemm(oB, pwT + (size_t)i * DD * DD, pb + i * DD, nullptr, h, h, nullptr,
                    TT, DD, DD, 0, stream);

        hipLaunchKernelGGL(ln_kernel, dim3(TT), dim3(DD), 0, stream,
                           h, ln2s + i * DD, ln2b + i * DD, y);
        launch_gemm(y, f1wT + (size_t)i * DD * FF, f1b + i * FF, nullptr, nullptr,
                    nullptr, ffn, TT, FF, DD, 1, stream);
        launch_gemm(ffn, f2wT + (size_t)i * FF * DD, f2b + i * DD, nullptr, h,
                    (i == 0) ? h : nullptr, (i == 1) ? hbf : nullptr,
                    TT, DD, FF, 0, stream);
    }

    // 4) heads: fused layer-1 GEMM (N=768) -> t1 [T][768],
    //    then ONE fused layer-2 MFMA GEMM (N=384) scattering into outputs.
    hipLaunchKernelGGL(gemm_head1_kernel, dim3(768 / 64, TT / 64), dim3(256), 0, stream,
                       hbf, headT, cls_b1, box_b1, obj_b1, t1);

    float* cls_out = out;
    float* box_out = out + (size_t)BB * NA * NP * NC;
    float* obj_out = box_out + (size_t)BB * NA * NP * 4;

    hipLaunchKernelGGL(gemm_head2_kernel, dim3(384 / 64, TT / 64), dim3(256), 0, stream,
                       t1, head2T, cls_b2, box_b2, obj_b2, cls_out, box_out, obj_out);
}